// Round 8
// baseline (103.540 us; speedup 1.0000x reference)
//
#include <hip/hip_runtime.h>
#include <math.h>

#define NS   8      // samples
#define CC   256    // input channels
#define PP   961    // H*W
#define MM   7688   // NS*PP nodes
#define MP   7744   // MM padded to 64
#define HID  512
#define OUTC 256

typedef _Float16 h16;
using half8   = __attribute__((ext_vector_type(8))) _Float16;
using floatx4 = __attribute__((ext_vector_type(4))) float;

#define AS1 __attribute__((address_space(1)))
#define AS3 __attribute__((address_space(3)))

// deg = 963 for b in {0,7}, 964 otherwise; dinv = deg^-0.5
__device__ __forceinline__ float dinv_of(int b) {
    return (b == 0 || b == NS - 1) ? 0.0322245515f : 0.0322078318f;
}

// K0 prep: [0,256): W->fp16; [256,2240): transpose-cast x -> Xt (rho layout) + S1 tile
// partials (no atomics); [2240]: zero SY.
__global__ void prep(const float* __restrict__ W1, const float* __restrict__ W2,
                     h16* __restrict__ w1h, h16* __restrict__ w2h,
                     const float* __restrict__ x, h16* __restrict__ Xt,
                     float* __restrict__ S1p, float* __restrict__ SY) {
    int blk = blockIdx.x, tid = threadIdx.x;
    if (blk < 256) {
        bool second = blk >= 128;
        const float* src = second ? W2 : W1;
        h16* dst = second ? w2h : w1h;
        int i = ((blk & 127) * 256 + tid) * 4;
        float4 v = *(const float4*)(src + i);
        dst[i + 0] = (h16)v.x; dst[i + 1] = (h16)v.y;
        dst[i + 2] = (h16)v.z; dst[i + 3] = (h16)v.w;
    } else if (blk < 2240) {
        __shared__ h16 tr[32][33];
        int t = blk - 256;                       // < 1984 = 31(pt) * 8(ct) * 8(b)
        int b = t & 7, ct = (t >> 3) & 7, pt = t >> 6;
        int p0 = pt * 32, c0 = ct * 32;
        int j = tid & 31, i0 = tid >> 5;
        int p = p0 + j;
        #pragma unroll
        for (int r = 0; r < 4; ++r) {
            int c = c0 + i0 + r * 8;
            float v = (p < PP) ? x[((size_t)b * CC + c) * PP + p] : 0.f;
            tr[i0 + r * 8][j] = (h16)v;
        }
        __syncthreads();
        #pragma unroll
        for (int r = 0; r < 4; ++r) {
            int ii = tid & 31;
            int jj = (tid >> 5) + r * 8;
            int pw = p0 + jj;
            if (pw < PP) {
                int row = ((pw >> 3) << 6) + (b << 3) + (pw & 7);   // rho
                Xt[(size_t)row * CC + c0 + ii] = tr[ii][jj];
            }
        }
        if (tid < 32) {   // S1 partial: sum over this tile's 32 p for c = c0+tid
            float s = 0.f;
            #pragma unroll
            for (int jj = 0; jj < 32; ++jj) s += (float)tr[tid][jj];
            S1p[pt * (NS * CC) + b * CC + c0 + tid] = s;
        }
    } else {
        for (int i = tid; i < NS * OUTC; i += 256) SY[i] = 0.f;
    }
}

// K1 corr: SZc[b,h] = db^2 * sum_c S1[b,c] * W1[h,c]  (fp32, from fp32 W1)
__global__ void corr(const float* __restrict__ S1p, const float* __restrict__ W1,
                     float* __restrict__ SZc) {
    __shared__ float s1[CC];
    int b = blockIdx.x >> 2, hq = blockIdx.x & 3;
    int tid = threadIdx.x;
    if (tid < CC) {
        float s = 0.f;
        for (int pt = 0; pt < 31; ++pt) s += S1p[pt * (NS * CC) + b * CC + tid];
        s1[tid] = s;
    }
    __syncthreads();
    if (tid < 128) {
        int h = hq * 128 + tid;
        const float* wr = W1 + (size_t)h * CC;
        float dot = 0.f;
        for (int c = 0; c < CC; c += 4) {
            float4 w = *(const float4*)(wr + c);
            dot += s1[c] * w.x + s1[c + 1] * w.y + s1[c + 2] * w.z + s1[c + 3] * w.w;
        }
        float db = dinv_of(b);
        SZc[b * HID + h] = db * db * dot;
    }
}

// K2: gemm1 with fused layer-1 adjacency. Stages Xt slice (rho rows: neighbors b+-1
// are rows +-8 in-tile), producer threads build G = db^2*X + db*dm*X[-8] + db*dp*X[+8]
// in LDS (reg coefficients, no global loads in loop), MFMA vs W1.
// Epilogue: H1 = lrelu(acc + SZc[b,col] + b1[col]); invalid-p rows forced to 0.
__global__ __launch_bounds__(256) void gemm1_rho(
    const h16* __restrict__ Xt,    // [MP][CC] rho rows
    const h16* __restrict__ B,     // w1h [HID][CC]
    const float* __restrict__ SZc, // [NS][HID]
    const float* __restrict__ b1v, // [HID]
    h16* __restrict__ H1)          // [MP][HID] rho rows
{
    __shared__ __align__(16) h16 Xs[64 * 64];
    __shared__ __align__(16) h16 Gs[64 * 64];
    __shared__ __align__(16) h16 Bs[64 * 64];
    int tid = threadIdx.x, wave = tid >> 6, lane = tid & 63;
    int rt = blockIdx.x, n0 = blockIdx.y * 64;
    int sro = lane >> 3;
    int sch = (lane & 7) ^ sro;
    const h16* gx0 = Xt + (size_t)(rt * 64 + wave * 16 + sro) * CC + sch * 8;
    const h16* gb0 = B + (size_t)(n0 + wave * 16 + sro) * CC + sch * 8;
    h16* lx0 = &Xs[(wave * 16) * 64];
    h16* lx1 = &Xs[(wave * 16 + 8) * 64];
    h16* lb0 = &Bs[(wave * 16) * 64];
    h16* lb1 = &Bs[(wave * 16 + 8) * 64];
    int fr = lane & 15, fq = lane >> 4;
    // producer mapping: thread -> row hr, chunk pair hc0
    int hr = tid >> 2, hc0 = (tid & 3) * 2;
    int hb = hr >> 3;
    float db  = dinv_of(hb);
    float db2 = db * db;
    float dmw = (hb > 0)      ? db * dinv_of(hb - 1) : 0.f;
    float dpw = (hb < NS - 1) ? db * dinv_of(hb + 1) : 0.f;
    int hrm = (hb > 0)      ? hr - 8 : hr;   // clamped: coeff exactly 0
    int hrp = (hb < NS - 1) ? hr + 8 : hr;
    floatx4 acc[4] = {{0.f,0.f,0.f,0.f},{0.f,0.f,0.f,0.f},{0.f,0.f,0.f,0.f},{0.f,0.f,0.f,0.f}};
    for (int kk = 0; kk < CC; kk += 64) {
        __builtin_amdgcn_global_load_lds((const AS1 void*)(const void*)(gx0 + kk),
                                         (AS3 void*)(void*)lx0, 16, 0, 0);
        __builtin_amdgcn_global_load_lds((const AS1 void*)(const void*)(gx0 + 8 * CC + kk),
                                         (AS3 void*)(void*)lx1, 16, 0, 0);
        __builtin_amdgcn_global_load_lds((const AS1 void*)(const void*)(gb0 + kk),
                                         (AS3 void*)(void*)lb0, 16, 0, 0);
        __builtin_amdgcn_global_load_lds((const AS1 void*)(const void*)(gb0 + 8 * CC + kk),
                                         (AS3 void*)(void*)lb1, 16, 0, 0);
        __syncthreads();
        #pragma unroll
        for (int qi = 0; qi < 2; ++qi) {
            int ch = hc0 + qi;
            int slot = ch ^ (hr & 7);          // same slot valid for hr, hr+-8
            half8 zc = *(const half8*)&Xs[hr  * 64 + slot * 8];
            half8 zm = *(const half8*)&Xs[hrm * 64 + slot * 8];
            half8 zp = *(const half8*)&Xs[hrp * 64 + slot * 8];
            half8 o;
            #pragma unroll
            for (int j = 0; j < 8; ++j)
                o[j] = (h16)(db2 * (float)zc[j] + dmw * (float)zm[j] + dpw * (float)zp[j]);
            *(half8*)&Gs[hr * 64 + slot * 8] = o;
        }
        __syncthreads();
        #pragma unroll
        for (int ks = 0; ks < 2; ++ks) {
            int slot = (ks * 4 + fq) ^ (fr & 7);
            half8 bf = *(const half8*)&Bs[(wave * 16 + fr) * 64 + slot * 8];
            #pragma unroll
            for (int mb = 0; mb < 4; ++mb) {
                half8 af = *(const half8*)&Gs[(mb * 16 + fr) * 64 + slot * 8];
                acc[mb] = __builtin_amdgcn_mfma_f32_16x16x32_f16(af, bf, acc[mb], 0, 0, 0);
            }
        }
        __syncthreads();
    }
    int col = n0 + wave * 16 + fr;
    float bv = b1v[col];
    #pragma unroll
    for (int mb = 0; mb < 4; ++mb) {
        #pragma unroll
        for (int r = 0; r < 4; ++r) {
            int row = 16 * mb + 4 * fq + r;
            int b = row >> 3;
            int p = rt * 8 + (row & 7);
            float v = acc[mb][r] + SZc[b * HID + col] + bv;
            v = (v >= 0.f) ? v : 0.01f * v;
            H1[(size_t)(rt * 64 + row) * HID + col] = (p < PP) ? (h16)v : (h16)0.f;
        }
    }
}

// K3: plain MFMA GEMM (R4-proven structure): Y = H1 @ W2^T raw + per-sample colsums SY.
// rho rows: acc row -> b = row>>3 (in-tile).
__global__ __launch_bounds__(256) void gemm2_sy(
    const h16* __restrict__ A,     // H1 [MP][HID] rho rows
    const h16* __restrict__ B,     // w2h [OUTC][HID]
    float* __restrict__ Y,         // [MP][OUTC] rho rows
    float* __restrict__ SY)        // [NS][OUTC]
{
    __shared__ __align__(16) h16 As[64 * 64];
    __shared__ __align__(16) h16 Bs[64 * 64];
    int tid = threadIdx.x, wave = tid >> 6, lane = tid & 63;
    int rt = blockIdx.x, n0 = blockIdx.y * 64;
    int sro = lane >> 3;
    int sch = (lane & 7) ^ sro;
    const h16* ga0 = A + (size_t)(rt * 64 + wave * 16 + sro) * HID + sch * 8;
    const h16* gb0 = B + (size_t)(n0 + wave * 16 + sro) * HID + sch * 8;
    h16* la0 = &As[(wave * 16) * 64];
    h16* la1 = &As[(wave * 16 + 8) * 64];
    h16* lb0 = &Bs[(wave * 16) * 64];
    h16* lb1 = &Bs[(wave * 16 + 8) * 64];
    int fr = lane & 15, fq = lane >> 4;
    floatx4 acc[4] = {{0.f,0.f,0.f,0.f},{0.f,0.f,0.f,0.f},{0.f,0.f,0.f,0.f},{0.f,0.f,0.f,0.f}};
    for (int kk = 0; kk < HID; kk += 64) {
        __builtin_amdgcn_global_load_lds((const AS1 void*)(const void*)(ga0 + kk),
                                         (AS3 void*)(void*)la0, 16, 0, 0);
        __builtin_amdgcn_global_load_lds((const AS1 void*)(const void*)(ga0 + 8 * HID + kk),
                                         (AS3 void*)(void*)la1, 16, 0, 0);
        __builtin_amdgcn_global_load_lds((const AS1 void*)(const void*)(gb0 + kk),
                                         (AS3 void*)(void*)lb0, 16, 0, 0);
        __builtin_amdgcn_global_load_lds((const AS1 void*)(const void*)(gb0 + 8 * HID + kk),
                                         (AS3 void*)(void*)lb1, 16, 0, 0);
        __syncthreads();
        #pragma unroll
        for (int ks = 0; ks < 2; ++ks) {
            int slot = (ks * 4 + fq) ^ (fr & 7);
            half8 bf = *(const half8*)&Bs[(wave * 16 + fr) * 64 + slot * 8];
            #pragma unroll
            for (int mb = 0; mb < 4; ++mb) {
                half8 af = *(const half8*)&As[(mb * 16 + fr) * 64 + slot * 8];
                acc[mb] = __builtin_amdgcn_mfma_f32_16x16x32_f16(af, bf, acc[mb], 0, 0, 0);
            }
        }
        __syncthreads();
    }
    int col = n0 + wave * 16 + fr;
    size_t row0 = (size_t)rt * 64;
    float sb[4];
    #pragma unroll
    for (int mb = 0; mb < 4; ++mb) {
        float s = 0.f;
        #pragma unroll
        for (int r = 0; r < 4; ++r) {
            int row = 16 * mb + 4 * fq + r;
            float v = acc[mb][r];
            Y[(row0 + row) * OUTC + col] = v;
            s += v;
        }
        sb[mb] = s;
    }
    #pragma unroll
    for (int mb = 0; mb < 4; ++mb) sb[mb] += __shfl_xor(sb[mb], 16);
    if (fq == 0 || fq == 2) {
        int bodd = (fq >= 2) ? 1 : 0;
        #pragma unroll
        for (int mb = 0; mb < 4; ++mb)
            atomicAdd(&SY[(2 * mb + bodd) * OUTC + col], sb[mb]);
    }
}

// K4: out[o*PP+p] = max_b lrelu( b2[o] + db*( db*(SY[b,o]+Y[b,p,o]) + dm*Y[b-1,p,o] + dp*Y[b+1,p,o] ) )
// Y in rho layout: row(b,p) = (p>>3)*64 + b*8 + (p&7)
__global__ void final_max(const float* __restrict__ Y, const float* __restrict__ SY,
                          const float* __restrict__ b2, float* __restrict__ out) {
    int pt = blockIdx.x, ot = blockIdx.y;
    int p0 = pt * 32, o0 = ot * 32;
    __shared__ float t[32][33];
    int i = threadIdx.x & 31, j0 = threadIdx.x >> 5;
    int o = o0 + i;
    float bias = b2[o];
    #pragma unroll
    for (int r = 0; r < 4; ++r) {
        int j = j0 + r * 8;
        int p = p0 + j;
        float vmax = -INFINITY;
        if (p < PP) {
            size_t rbase = (size_t)(((p >> 3) << 6) + (p & 7)) * OUTC + o;
            float y[NS];
            #pragma unroll
            for (int b = 0; b < NS; ++b)
                y[b] = Y[rbase + (size_t)b * 8 * OUTC];
            #pragma unroll
            for (int b = 0; b < NS; ++b) {
                float db = dinv_of(b);
                float a = db * (SY[b * OUTC + o] + y[b]);
                if (b > 0)      a += dinv_of(b - 1) * y[b - 1];
                if (b < NS - 1) a += dinv_of(b + 1) * y[b + 1];
                float z = db * a + bias;
                z = (z >= 0.f) ? z : 0.01f * z;
                vmax = fmaxf(vmax, z);
            }
        }
        t[j][i] = vmax;
    }
    __syncthreads();
    int jj = threadIdx.x & 31, ii0 = threadIdx.x >> 5;
    #pragma unroll
    for (int r = 0; r < 4; ++r) {
        int ii = ii0 + r * 8;
        int pw = p0 + jj;
        if (pw < PP)
            out[(size_t)(o0 + ii) * PP + pw] = t[jj][ii];
    }
}

extern "C" void kernel_launch(void* const* d_in, const int* in_sizes, int n_in,
                              void* d_out, int out_size, void* d_ws, size_t ws_size,
                              hipStream_t stream) {
    const float* x  = (const float*)d_in[0];
    const float* W1 = (const float*)d_in[1];
    const float* b1 = (const float*)d_in[2];
    const float* W2 = (const float*)d_in[3];
    const float* b2 = (const float*)d_in[4];
    float* out = (float*)d_out;
    float* ws  = (float*)d_ws;

    // workspace layout (float offsets, 16B-aligned)
    float* S1p = ws;                             //   63,488 f (31 x 8 x 256)
    float* SZc = ws + 63488;                     //    4,096 f
    float* SY  = ws + 67584;                     //    2,048 f
    h16*  w1h  = (h16*)(ws + 69632);             //  131,072 h = 65,536 f
    h16*  w2h  = (h16*)(ws + 135168);            //  131,072 h
    h16*  Xt   = (h16*)(ws + 200704);            //  MP*CC  h = 991,232 f (rho; pad rows poison->masked)
    h16*  H1   = (h16*)(ws + 1191936);           //  MP*HID h = 1,982,464 f (rho; pad rows zeroed)
    float* Y   = ws + 3174400;                   //  MP*OUTC f = 1,982,464 f -> end 5,156,864 f (20.6 MB)

    prep<<<2241, 256, 0, stream>>>(W1, W2, w1h, w2h, x, Xt, S1p, SY);
    corr<<<32, 256, 0, stream>>>(S1p, W1, SZc);
    gemm1_rho<<<dim3(MP / 64, HID / 64), 256, 0, stream>>>(Xt, w1h, SZc, b1, H1);
    gemm2_sy<<<dim3(MP / 64, OUTC / 64), 256, 0, stream>>>(H1, w2h, Y, SY);
    final_max<<<dim3(31, 8), 256, 0, stream>>>(Y, SY, b2, out);
}

// Round 9
// 99.312 us; speedup vs baseline: 1.0426x; 1.0426x over previous
//
#include <hip/hip_runtime.h>
#include <math.h>

#define NS   8      // samples
#define CC   256    // input channels
#define PP   961    // H*W
#define MM   7688   // NS*PP nodes
#define MP   7744   // MM padded to 64 (121 rho tiles cover p 0..967)
#define MPX  7808   // MP + 64 (appended tile 121: rows 7744+b hold db^2*S1[b,:])
#define HID  512
#define OUTC 256

typedef _Float16 h16;
using half8   = __attribute__((ext_vector_type(8))) _Float16;
using floatx4 = __attribute__((ext_vector_type(4))) float;

#define AS1 __attribute__((address_space(1)))
#define AS3 __attribute__((address_space(3)))

// deg = 963 for b in {0,7}, 964 otherwise; dinv = deg^-0.5
__device__ __forceinline__ float dinv_of(int b) {
    return (b == 0 || b == NS - 1) ? 0.0322245515f : 0.0322078318f;
}

// K0 prep (one kernel, independent block groups):
//  [0,248):     transpose+combine: read all 8 b-planes of a (32p x 32c) x-tile,
//               write G rho rows = db^2*x[b] + db*d(b-1)*x[b-1] + db*d(b+1)*x[b+1]
//  [248,2296):  colsum (b,c): G[7744+b][c] = (h16)(db^2 * sum_p x[b,c,p])
//  [2296,2552): W1/W2 -> fp16
//  [2552]:      zero SY + zero G pad rows 7752..7807
__global__ void prep(const float* __restrict__ W1, const float* __restrict__ W2,
                     h16* __restrict__ w1h, h16* __restrict__ w2h,
                     const float* __restrict__ x, h16* __restrict__ G,
                     float* __restrict__ SY) {
    int blk = blockIdx.x, tid = threadIdx.x;
    if (blk < 248) {
        __shared__ float tr[8][32][33];
        int pt = blk % 31, ct = blk / 31;
        int p0 = pt * 32, c0 = ct * 32;
        int j = tid & 31, i0 = tid >> 5;
        int p = p0 + j;
        bool pv = (p < PP);
        #pragma unroll
        for (int b = 0; b < NS; ++b)
            #pragma unroll
            for (int r = 0; r < 4; ++r) {
                int c = c0 + i0 + r * 8;
                tr[b][i0 + r * 8][j] = pv ? x[((size_t)b * CC + c) * PP + p] : 0.f;
            }
        __syncthreads();
        int ii = tid & 31, jj0 = tid >> 5;
        #pragma unroll
        for (int b = 0; b < NS; ++b) {
            float db  = dinv_of(b);
            float db2 = db * db;
            float dmw = (b > 0)      ? db * dinv_of(b - 1) : 0.f;
            float dpw = (b < NS - 1) ? db * dinv_of(b + 1) : 0.f;
            #pragma unroll
            for (int r = 0; r < 4; ++r) {
                int pj = jj0 + r * 8;
                int pw = p0 + pj;
                if (pw < 968) {                      // rho rows exist for p < 968
                    float v = 0.f;
                    if (pw < PP) {
                        v = db2 * tr[b][ii][pj];
                        if (b > 0)      v += dmw * tr[b - 1][ii][pj];
                        if (b < NS - 1) v += dpw * tr[b + 1][ii][pj];
                    }
                    int row = ((pw >> 3) << 6) + (b << 3) + (pw & 7);
                    G[(size_t)row * CC + c0 + ii] = (h16)v;
                }
            }
        }
    } else if (blk < 2296) {
        int t = blk - 248;
        int b = t >> 8, c = t & 255;
        const float* src = x + ((size_t)b * CC + c) * PP;
        float s = 0.f;
        for (int i = tid; i < PP; i += 256) s += src[i];
        __shared__ float red[256];
        red[tid] = s;
        __syncthreads();
        for (int off = 128; off > 0; off >>= 1) {
            if (tid < off) red[tid] += red[tid + off];
            __syncthreads();
        }
        if (tid == 0) {
            float db = dinv_of(b);
            G[(size_t)(MP + b) * CC + c] = (h16)(db * db * red[0]);
        }
    } else if (blk < 2552) {
        int t = blk - 2296;
        bool second = t >= 128;
        const float* src = second ? W2 : W1;
        h16* dst = second ? w2h : w1h;
        int i = ((t & 127) * 256 + tid) * 4;
        float4 v = *(const float4*)(src + i);
        dst[i + 0] = (h16)v.x; dst[i + 1] = (h16)v.y;
        dst[i + 2] = (h16)v.z; dst[i + 3] = (h16)v.w;
    } else {
        for (int i = tid; i < NS * OUTC; i += 256) SY[i] = 0.f;
        for (int i = tid; i < 56 * CC; i += 256)
            G[(size_t)(MP + NS) * CC + i] = (h16)0.f;   // rows 7752..7807
    }
}

// K1: plain MFMA GEMM: H1ext = G @ W1^T (raw, fp16 out). 64x64 tile, BK=64,
// XOR-swizzled LDS, 2 barriers/K-step. Tile rt==121 rows are db^2*S1 -> its
// output rows (7744+b) become SZb1[b,:] after adding b1 in the epilogue.
__global__ __launch_bounds__(256) void gemm1(
    const h16* __restrict__ A,     // G [MPX][CC]
    const h16* __restrict__ B,     // w1h [HID][CC]
    const float* __restrict__ b1v, // [HID]
    h16* __restrict__ H1)          // [MPX][HID]
{
    __shared__ __align__(16) h16 As[64 * 64];
    __shared__ __align__(16) h16 Bs[64 * 64];
    int tid = threadIdx.x, wave = tid >> 6, lane = tid & 63;
    int rt = blockIdx.x, n0 = blockIdx.y * 64;
    int sro = lane >> 3;
    int sch = (lane & 7) ^ sro;
    const h16* ga0 = A + (size_t)(rt * 64 + wave * 16 + sro) * CC + sch * 8;
    const h16* gb0 = B + (size_t)(n0 + wave * 16 + sro) * CC + sch * 8;
    h16* la0 = &As[(wave * 16) * 64];
    h16* la1 = &As[(wave * 16 + 8) * 64];
    h16* lb0 = &Bs[(wave * 16) * 64];
    h16* lb1 = &Bs[(wave * 16 + 8) * 64];
    int fr = lane & 15, fq = lane >> 4;
    floatx4 acc[4] = {{0.f,0.f,0.f,0.f},{0.f,0.f,0.f,0.f},{0.f,0.f,0.f,0.f},{0.f,0.f,0.f,0.f}};
    for (int kk = 0; kk < CC; kk += 64) {
        __builtin_amdgcn_global_load_lds((const AS1 void*)(const void*)(ga0 + kk),
                                         (AS3 void*)(void*)la0, 16, 0, 0);
        __builtin_amdgcn_global_load_lds((const AS1 void*)(const void*)(ga0 + 8 * CC + kk),
                                         (AS3 void*)(void*)la1, 16, 0, 0);
        __builtin_amdgcn_global_load_lds((const AS1 void*)(const void*)(gb0 + kk),
                                         (AS3 void*)(void*)lb0, 16, 0, 0);
        __builtin_amdgcn_global_load_lds((const AS1 void*)(const void*)(gb0 + 8 * CC + kk),
                                         (AS3 void*)(void*)lb1, 16, 0, 0);
        __syncthreads();
        #pragma unroll
        for (int ks = 0; ks < 2; ++ks) {
            int slot = (ks * 4 + fq) ^ (fr & 7);
            half8 bf = *(const half8*)&Bs[(wave * 16 + fr) * 64 + slot * 8];
            #pragma unroll
            for (int mb = 0; mb < 4; ++mb) {
                half8 af = *(const half8*)&As[(mb * 16 + fr) * 64 + slot * 8];
                acc[mb] = __builtin_amdgcn_mfma_f32_16x16x32_f16(af, bf, acc[mb], 0, 0, 0);
            }
        }
        __syncthreads();
    }
    int col = n0 + wave * 16 + fr;
    float bv = (rt == MP / 64) ? b1v[col] : 0.f;   // appended tile: +b1 -> SZb1 rows
    size_t row0 = (size_t)rt * 64;
    #pragma unroll
    for (int mb = 0; mb < 4; ++mb)
        #pragma unroll
        for (int r = 0; r < 4; ++r) {
            int row = 16 * mb + 4 * fq + r;
            H1[(row0 + row) * HID + col] = (h16)(acc[mb][r] + bv);
        }
}

// K2: GEMM2 with register-staged A applying the layer-1 nonlinearity on the fly:
// Hs = pvalid ? lrelu(H1raw + SZb1[b,k]) : 0, written straight to LDS (still 2
// barriers/K-step). B via global_load_lds. Epilogue: Y raw + per-sample colsums SY.
__global__ __launch_bounds__(256) void gemm2(
    const h16* __restrict__ A,     // H1ext [MPX][HID]; rows 7744+b = SZb1
    const h16* __restrict__ B,     // w2h [OUTC][HID]
    float* __restrict__ Y,         // [MP][OUTC] rho rows
    float* __restrict__ SY)        // [NS][OUTC]
{
    __shared__ __align__(16) h16 As[64 * 64];
    __shared__ __align__(16) h16 Bs[64 * 64];
    int tid = threadIdx.x, wave = tid >> 6, lane = tid & 63;
    int rt = blockIdx.x, n0 = blockIdx.y * 64;
    int sro = lane >> 3;
    int sch = lane & 7;                   // natural chunk; LDS slot = sch ^ (row&7)
    int schB = sch ^ sro;                 // B keeps the async-load swizzle mapping
    const h16* ga0 = A + (size_t)(rt * 64 + wave * 16 + sro) * HID + sch * 8;
    const h16* gb0 = B + (size_t)(n0 + wave * 16 + sro) * HID + schB * 8;
    int b0 = wave * 2;                    // b of staged row wave*16+sro (rho)
    const h16* gt0 = A + (size_t)(MP + b0) * HID + sch * 8;       // SZb1[b0]
    const h16* gt1 = A + (size_t)(MP + b0 + 1) * HID + sch * 8;   // SZb1[b0+1]
    bool pv = (rt * 8 + sro) < PP;        // same p for both staged rows
    h16* lb0 = &Bs[(wave * 16) * 64];
    h16* lb1 = &Bs[(wave * 16 + 8) * 64];
    int slotA = (sch ^ sro) * 8;
    h16* lw0 = &As[(wave * 16 + sro) * 64 + slotA];
    h16* lw1 = &As[(wave * 16 + 8 + sro) * 64 + slotA];
    int fr = lane & 15, fq = lane >> 4;
    floatx4 acc[4] = {{0.f,0.f,0.f,0.f},{0.f,0.f,0.f,0.f},{0.f,0.f,0.f,0.f},{0.f,0.f,0.f,0.f}};
    for (int kk = 0; kk < HID; kk += 64) {
        __builtin_amdgcn_global_load_lds((const AS1 void*)(const void*)(gb0 + kk),
                                         (AS3 void*)(void*)lb0, 16, 0, 0);
        __builtin_amdgcn_global_load_lds((const AS1 void*)(const void*)(gb0 + 8 * HID + kk),
                                         (AS3 void*)(void*)lb1, 16, 0, 0);
        half8 a0 = *(const half8*)(ga0 + kk);
        half8 a1 = *(const half8*)(ga0 + 8 * HID + kk);
        half8 t0 = *(const half8*)(gt0 + kk);
        half8 t1 = *(const half8*)(gt1 + kk);
        half8 o0, o1;
        #pragma unroll
        for (int j = 0; j < 8; ++j) {
            float v0 = (float)a0[j] + (float)t0[j];
            float v1 = (float)a1[j] + (float)t1[j];
            v0 = (v0 >= 0.f) ? v0 : 0.01f * v0;
            v1 = (v1 >= 0.f) ? v1 : 0.01f * v1;
            o0[j] = pv ? (h16)v0 : (h16)0.f;
            o1[j] = pv ? (h16)v1 : (h16)0.f;
        }
        *(half8*)lw0 = o0;
        *(half8*)lw1 = o1;
        __syncthreads();
        #pragma unroll
        for (int ks = 0; ks < 2; ++ks) {
            int slot = (ks * 4 + fq) ^ (fr & 7);
            half8 bf = *(const half8*)&Bs[(wave * 16 + fr) * 64 + slot * 8];
            #pragma unroll
            for (int mb = 0; mb < 4; ++mb) {
                half8 af = *(const half8*)&As[(mb * 16 + fr) * 64 + slot * 8];
                acc[mb] = __builtin_amdgcn_mfma_f32_16x16x32_f16(af, bf, acc[mb], 0, 0, 0);
            }
        }
        __syncthreads();
    }
    int col = n0 + wave * 16 + fr;
    size_t row0 = (size_t)rt * 64;
    float sb[4];
    #pragma unroll
    for (int mb = 0; mb < 4; ++mb) {
        float s = 0.f;
        #pragma unroll
        for (int r = 0; r < 4; ++r) {
            int row = 16 * mb + 4 * fq + r;
            float v = acc[mb][r];
            Y[(row0 + row) * OUTC + col] = v;
            s += v;
        }
        sb[mb] = s;
    }
    #pragma unroll
    for (int mb = 0; mb < 4; ++mb) sb[mb] += __shfl_xor(sb[mb], 16);
    if (fq == 0 || fq == 2) {
        int bodd = (fq >= 2) ? 1 : 0;
        #pragma unroll
        for (int mb = 0; mb < 4; ++mb)
            atomicAdd(&SY[(2 * mb + bodd) * OUTC + col], sb[mb]);
    }
}

// K3: out[o*PP+p] = max_b lrelu( b2[o] + db*( db*(SY[b,o]+Y[b,p,o]) + dm*Y[b-1,p,o] + dp*Y[b+1,p,o] ) )
// Y in rho layout: row(b,p) = (p>>3)*64 + b*8 + (p&7)
__global__ void final_max(const float* __restrict__ Y, const float* __restrict__ SY,
                          const float* __restrict__ b2, float* __restrict__ out) {
    int pt = blockIdx.x, ot = blockIdx.y;
    int p0 = pt * 32, o0 = ot * 32;
    __shared__ float t[32][33];
    int i = threadIdx.x & 31, j0 = threadIdx.x >> 5;
    int o = o0 + i;
    float bias = b2[o];
    #pragma unroll
    for (int r = 0; r < 4; ++r) {
        int j = j0 + r * 8;
        int p = p0 + j;
        float vmax = -INFINITY;
        if (p < PP) {
            size_t rbase = (size_t)(((p >> 3) << 6) + (p & 7)) * OUTC + o;
            float y[NS];
            #pragma unroll
            for (int b = 0; b < NS; ++b)
                y[b] = Y[rbase + (size_t)b * 8 * OUTC];
            #pragma unroll
            for (int b = 0; b < NS; ++b) {
                float db = dinv_of(b);
                float a = db * (SY[b * OUTC + o] + y[b]);
                if (b > 0)      a += dinv_of(b - 1) * y[b - 1];
                if (b < NS - 1) a += dinv_of(b + 1) * y[b + 1];
                float z = db * a + bias;
                z = (z >= 0.f) ? z : 0.01f * z;
                vmax = fmaxf(vmax, z);
            }
        }
        t[j][i] = vmax;
    }
    __syncthreads();
    int jj = threadIdx.x & 31, ii0 = threadIdx.x >> 5;
    #pragma unroll
    for (int r = 0; r < 4; ++r) {
        int ii = ii0 + r * 8;
        int pw = p0 + jj;
        if (pw < PP)
            out[(size_t)(o0 + ii) * PP + pw] = t[jj][ii];
    }
}

extern "C" void kernel_launch(void* const* d_in, const int* in_sizes, int n_in,
                              void* d_out, int out_size, void* d_ws, size_t ws_size,
                              hipStream_t stream) {
    const float* x  = (const float*)d_in[0];
    const float* W1 = (const float*)d_in[1];
    const float* b1 = (const float*)d_in[2];
    const float* W2 = (const float*)d_in[3];
    const float* b2 = (const float*)d_in[4];
    float* out = (float*)d_out;
    float* ws  = (float*)d_ws;

    // workspace layout (float offsets, 16B-aligned)
    float* SY  = ws;                             //      2,048 f
    h16*  w1h  = (h16*)(ws + 2048);              //  131,072 h =  65,536 f
    h16*  w2h  = (h16*)(ws + 67584);             //  131,072 h
    h16*  G    = (h16*)(ws + 133120);            //  MPX*CC  h =   999,424 f
    h16*  H1   = (h16*)(ws + 1132544);           //  MPX*HID h = 1,998,848 f
    float* Y   = ws + 3131392;                   //  MP*OUTC f = 1,982,464 f -> end 5,113,856 f (20.5 MB)

    prep<<<2553, 256, 0, stream>>>(W1, W2, w1h, w2h, x, G, SY);
    gemm1<<<dim3(MPX / 64, HID / 64), 256, 0, stream>>>(G, w1h, b1, H1);
    gemm2<<<dim3(MP / 64, OUTC / 64), 256, 0, stream>>>(H1, w2h, Y, SY);
    final_max<<<dim3(31, 8), 256, 0, stream>>>(Y, SY, b2, out);
}